// Round 11
// baseline (121.948 us; speedup 1.0000x reference)
//
#include <hip/hip_runtime.h>
#include <math.h>

#define BSH 9                       // 512 nodes per bucket
#define BMASK ((1 << BSH) - 1)
#define CAP 12288                   // per-bucket pair capacity (mean 8676, sigma 93)
#define ACH 2048                    // edges per scatA block

typedef unsigned int uint;
typedef __attribute__((ext_vector_type(8))) short bf16x8;
typedef __attribute__((ext_vector_type(4))) float f32x4;
typedef __attribute__((ext_vector_type(2))) float f32x2;

static __device__ __forceinline__ unsigned short f2bf(float f) {
    uint u = __float_as_uint(f);
    return (unsigned short)((u + 0x7fffu + ((u >> 16) & 1u)) >> 16);
}

// pack 8 consecutive fp32 (two float4) -> bf16x8 via HW cvt (RNE), src0 -> low half
static __device__ __forceinline__ bf16x8 pack8(float4 a, float4 b) {
    uint p0, p1, p2, p3;
    asm("v_cvt_pk_bf16_f32 %0, %1, %2" : "=v"(p0) : "v"(a.x), "v"(a.y));
    asm("v_cvt_pk_bf16_f32 %0, %1, %2" : "=v"(p1) : "v"(a.z), "v"(a.w));
    asm("v_cvt_pk_bf16_f32 %0, %1, %2" : "=v"(p2) : "v"(b.x), "v"(b.y));
    asm("v_cvt_pk_bf16_f32 %0, %1, %2" : "=v"(p3) : "v"(b.z), "v"(b.w));
    uint4 u = make_uint4(p0, p1, p2, p3);
    return *(bf16x8*)&u;
}

static __device__ __forceinline__ f32x2 dec2(uint u) {
    f32x2 r;
    r.x = __uint_as_float(u << 16);
    r.y = __uint_as_float(u & 0xffff0000u);
    return r;
}

static __device__ __forceinline__ f32x2 abs2(f32x2 h) {
    f32x2 r;
    r.x = __uint_as_float(__float_as_uint(h.x) & 0x7fffffffu);
    r.y = __uint_as_float(__float_as_uint(h.y) & 0x7fffffffu);
    return r;
}

// sum over 4-lane quads via DPP (no LDS port): xor1 then xor2
static __device__ __forceinline__ float qsum(float p) {
    p += __uint_as_float(__builtin_amdgcn_mov_dpp(__float_as_uint(p), 0xB1, 0xF, 0xF, true));
    p += __uint_as_float(__builtin_amdgcn_mov_dpp(__float_as_uint(p), 0x4E, 0xF, 0xF, true));
    return p;
}

// ---------------- prep: Wt[n][k] = bf16( (n<64?Wl:Wr)[k][n%64] ), 128x128 ----------------
// 8 blocks, block b owns k in [b*16, b*16+16). LDS-staged transpose, coalesced both sides.
__global__ __launch_bounds__(256) void k_prep(const float* __restrict__ Wl,
                                              const float* __restrict__ Wr,
                                              unsigned short* __restrict__ Wt) {
    __shared__ unsigned short s[16][130];   // [k_local][n], +2 pad
    int b = blockIdx.x;
    int t = threadIdx.x;
#pragma unroll
    for (int i = 0; i < 8; ++i) {
        int idx = i * 256 + t;              // 0..2047
        int kl = idx >> 7;                  // 0..15
        int n  = idx & 127;
        int k  = b * 16 + kl;
        float v = (n < 64) ? Wl[k * 64 + n] : Wr[k * 64 + (n - 64)];
        s[kl][n] = f2bf(v);
    }
    __syncthreads();
#pragma unroll
    for (int i = 0; i < 2; ++i) {
        int idx = i * 256 + t;              // 0..511
        int n  = idx >> 2;
        int kg = idx & 3;
        ushort4 v;
        v.x = s[kg * 4 + 0][n]; v.y = s[kg * 4 + 1][n];
        v.z = s[kg * 4 + 2][n]; v.w = s[kg * 4 + 3][n];
        *(ushort4*)(Wt + n * 128 + b * 16 + kg * 4) = v;
    }
}

// ---------------- MFMA dual GEMM body: [xl|xr] = x @ [Wl|Wr] + [bl|br] ----------------
// No LDS: B fragments read from the 32KB L1/L2-resident Wt table; A fragments read
// per-lane from x (one 128B line per (row, ks) covered by the 4 hi-groups) + cvt_pk.
static __device__ __forceinline__ void gemm_body(
        const float* __restrict__ x, const unsigned short* __restrict__ Wt,
        const float* __restrict__ bl, const float* __restrict__ br,
        unsigned short* __restrict__ xlh, float* __restrict__ xr, int N, int bid)
{
    const int t = threadIdx.x;
    const int base = bid * 128;
    const int w = t >> 6;               // wave 0..3
    const int lo = t & 15;              // lane low bits: A-row / B-col / D-col
    const int hi = (t & 63) >> 4;       // lane high bits: k-group / D-row-group
    int row0 = base + w * 32 + lo;
    int row1 = row0 + 16;
    const float4* x40 = (const float4*)x + (size_t)(row0 < N ? row0 : N - 1) * 32;
    const float4* x41 = (const float4*)x + (size_t)(row1 < N ? row1 : N - 1) * 32;

    f32x4 acc[2][8];
#pragma unroll
    for (int f = 0; f < 2; ++f)
#pragma unroll
        for (int j = 0; j < 8; ++j)
            acc[f][j] = (f32x4){0.f, 0.f, 0.f, 0.f};

#pragma unroll
    for (int ks = 0; ks < 4; ++ks) {
        int f4 = ks * 8 + hi * 2;       // float4 col of this lane's 8 fp32 k-values
        int kofs = ks * 32 + hi * 8;    // k element offset in Wt rows
        bf16x8 av[2], bv[8];
        av[0] = pack8(x40[f4], x40[f4 + 1]);
        av[1] = pack8(x41[f4], x41[f4 + 1]);
#pragma unroll
        for (int j = 0; j < 8; ++j) {
            int nn = j * 16 + lo;
            bv[j] = *(const bf16x8*)(Wt + nn * 128 + kofs);
        }
#pragma unroll
        for (int f = 0; f < 2; ++f)
#pragma unroll
            for (int j = 0; j < 8; ++j)
                acc[f][j] = __builtin_amdgcn_mfma_f32_16x16x32_bf16(av[f], bv[j], acc[f][j], 0, 0, 0);
    }

    // ---- epilogue: D[m][n], m = rbase + reg, n = j*16+lo ----
#pragma unroll
    for (int f = 0; f < 2; ++f) {
        int rbase = base + w * 32 + f * 16 + hi * 4;
#pragma unroll
        for (int j = 0; j < 8; ++j) {
            int nn = j * 16 + lo;
            float bvv = (j < 4) ? bl[nn] : br[nn - 64];
            float vv[4] = {acc[f][j][0] + bvv, acc[f][j][1] + bvv,
                           acc[f][j][2] + bvv, acc[f][j][3] + bvv};
            if (j < 4) {
#pragma unroll
                for (int q = 0; q < 4; ++q)
                    if (rbase + q < N) xlh[(size_t)(rbase + q) * 64 + nn] = f2bf(vv[q]);
            } else {
#pragma unroll
                for (int q = 0; q < 4; ++q)
                    if (rbase + q < N) xr[(size_t)(rbase + q) * 64 + (nn - 64)] = vv[q];
            }
        }
    }
}

// ---------------- scatA body: blocked coarse scatter into bucket-grouped packed pairs ----
// bcur starts at 0 (memset); bucket b's region is [b*CAP, b*CAP + count).
static __device__ __forceinline__ void scatA_body(
        const int* __restrict__ ei, int* __restrict__ bcur,
        unsigned* __restrict__ pairs, int E, int T, int NB, int bid)
{
    __shared__ int h[256];
    __shared__ int basem[256];
    int b0 = bid * ACH;
    int cnt = min(ACH, T - b0);
    h[threadIdx.x] = 0;
    __syncthreads();
    for (int i = threadIdx.x; i < cnt; i += 256) {
        int t = b0 + i;
        int d = (t < E) ? ei[E + t] : (t - E);
        atomicAdd(&h[d >> BSH], 1);
    }
    __syncthreads();
    if (threadIdx.x < NB) {
        int c = h[threadIdx.x];
        basem[threadIdx.x] = c ? (threadIdx.x * CAP + atomicAdd(&bcur[threadIdx.x], c)) : 0;
    }
    __syncthreads();
    h[threadIdx.x] = 0;
    __syncthreads();
    for (int i = threadIdx.x; i < cnt; i += 256) {
        int t = b0 + i;
        int s, d;
        if (t < E) { s = ei[t]; d = ei[E + t]; } else { s = t - E; d = s; }
        int b = d >> BSH;
        int idx = atomicAdd(&h[b], 1);
        pairs[basem[b] + idx] = ((unsigned)s << BSH) | (unsigned)(d & BMASK);
    }
}

// ---------------- fat kernel: blocks [0,GB) = gemm, [GB, GB+SB) = scatA ----------------
__global__ __launch_bounds__(256) void k_gs(const float* __restrict__ x,
        const unsigned short* __restrict__ Wt,
        const float* __restrict__ bl, const float* __restrict__ br,
        unsigned short* __restrict__ xlh, float* __restrict__ xr, int N,
        const int* __restrict__ ei, int* __restrict__ bcur,
        unsigned* __restrict__ pairs, int E, int T, int NB, int GB)
{
    if ((int)blockIdx.x < GB)
        gemm_body(x, Wt, bl, br, xlh, xr, N, blockIdx.x);
    else
        scatA_body(ei, bcur, pairs, E, T, NB, blockIdx.x - GB);
}

// ---------------- pass B: per-bucket degree count + scan + fine scatter + rowrng ----------------
__global__ __launch_bounds__(512) void k_scatB(const unsigned* __restrict__ pairs,
                                               const int* __restrict__ bcur,
                                               int* __restrict__ src_s, int2* __restrict__ rowrng, int N) {
    __shared__ int cnt[512];
    __shared__ int sm[512];
    __shared__ int lofs[512];
    int b = blockIdx.x;
    int beg = b * CAP, end = beg + bcur[b];
    int nbase = b << BSH;
    cnt[threadIdx.x] = 0;
    __syncthreads();
    for (int i = beg + threadIdx.x; i < end; i += 512)
        atomicAdd(&cnt[pairs[i] & BMASK], 1);
    __syncthreads();
    int v = cnt[threadIdx.x];
    sm[threadIdx.x] = v;
    __syncthreads();
    int acc = v;
    for (int off = 1; off < 512; off <<= 1) {
        int t = (threadIdx.x >= off) ? sm[threadIdx.x - off] : 0;
        __syncthreads();
        acc += t;
        sm[threadIdx.x] = acc;
        __syncthreads();
    }
    int excl = acc - v;
    lofs[threadIdx.x] = excl;
    int n = nbase + threadIdx.x;
    if (n < N) rowrng[n] = make_int2(beg + excl, beg + excl + v);
    cnt[threadIdx.x] = 0;
    __syncthreads();
    for (int i = beg + threadIdx.x; i < end; i += 512) {
        unsigned p = pairs[i];
        int dl = p & BMASK;
        int idx = atomicAdd(&cnt[dl], 1);
        src_s[beg + lofs[dl] + idx] = p >> BSH;
    }
}

// ---------------- fused attn + softmax + aggregation + silu ----------------
// 8 lanes per node, 8 channels per lane (bf16 gathers, 16 B/lane/edge).
// Lanes 0-3 = head0, lanes 4-7 = head1. 8 edges in flight.
// Packed f32x2 math; lrelu folded: att.lrelu(h) = (0.6 att).h + (0.4 att).|h|
__global__ __launch_bounds__(256) void k_fused(const int2* __restrict__ rowrng,
        const int* __restrict__ src_s, const unsigned short* __restrict__ xlh,
        const float* __restrict__ xr, const float* __restrict__ att,
        const float* __restrict__ bias, float* __restrict__ out, int N)
{
    int n = blockIdx.x * 32 + (threadIdx.x >> 3);
    int j = threadIdx.x & 7;
    if (n >= N) return;
    const uint4* xl4 = (const uint4*)xlh + j;
    f32x2 xr2[4], a06[4], a04[4];
    {
        float4 a = ((const float4*)xr)[(size_t)n * 16 + j * 2];
        float4 b = ((const float4*)xr)[(size_t)n * 16 + j * 2 + 1];
        xr2[0] = (f32x2){a.x, a.y}; xr2[1] = (f32x2){a.z, a.w};
        xr2[2] = (f32x2){b.x, b.y}; xr2[3] = (f32x2){b.z, b.w};
        float4 c = ((const float4*)att)[j * 2];
        float4 d = ((const float4*)att)[j * 2 + 1];
        a06[0] = (f32x2){0.6f * c.x, 0.6f * c.y}; a06[1] = (f32x2){0.6f * c.z, 0.6f * c.w};
        a06[2] = (f32x2){0.6f * d.x, 0.6f * d.y}; a06[3] = (f32x2){0.6f * d.z, 0.6f * d.w};
        a04[0] = (f32x2){0.4f * c.x, 0.4f * c.y}; a04[1] = (f32x2){0.4f * c.z, 0.4f * c.w};
        a04[2] = (f32x2){0.4f * d.x, 0.4f * d.y}; a04[3] = (f32x2){0.4f * d.z, 0.4f * d.w};
    }
    int2 rr = rowrng[n];
    float ssum = 0.f;
    f32x2 acc2[4] = {(f32x2){0.f,0.f}, (f32x2){0.f,0.f}, (f32x2){0.f,0.f}, (f32x2){0.f,0.f}};

#define EDGE_BODY(u)                                                      \
    {                                                                     \
        f32x2 v0 = dec2((u).x), v1 = dec2((u).y), v2 = dec2((u).z), v3 = dec2((u).w); \
        f32x2 h0 = v0 + xr2[0], h1 = v1 + xr2[1], h2 = v2 + xr2[2], h3 = v3 + xr2[3]; \
        f32x2 pa = h0 * a06[0]; pa += h1 * a06[1]; pa += h2 * a06[2]; pa += h3 * a06[3]; \
        pa += abs2(h0) * a04[0]; pa += abs2(h1) * a04[1];                 \
        pa += abs2(h2) * a04[2]; pa += abs2(h3) * a04[3];                 \
        float p = pa.x + pa.y;                                            \
        p = qsum(p);                                                      \
        float wq = __expf(p);                                             \
        ssum += wq;                                                       \
        f32x2 ws = (f32x2){wq, wq};                                       \
        acc2[0] += ws * v0; acc2[1] += ws * v1;                           \
        acc2[2] += ws * v2; acc2[3] += ws * v3;                           \
    }

    int i = rr.x;
    for (; i + 8 <= rr.y; i += 8) {
        uint4 u[8];
#pragma unroll
        for (int q = 0; q < 8; ++q)
            u[q] = xl4[((uint)src_s[i + q] << 3)];
#pragma unroll
        for (int q = 0; q < 8; ++q)
            EDGE_BODY(u[q]);
    }
    if (i + 4 <= rr.y) {
        uint4 u[4];
#pragma unroll
        for (int q = 0; q < 4; ++q)
            u[q] = xl4[((uint)src_s[i + q] << 3)];
#pragma unroll
        for (int q = 0; q < 4; ++q)
            EDGE_BODY(u[q]);
        i += 4;
    }
    for (; i < rr.y; ++i) {
        uint4 u0 = xl4[((uint)src_s[i] << 3)];
        EDGE_BODY(u0);
    }
#undef EDGE_BODY

    float inv = 1.f / ssum;
    float o[8];
#pragma unroll
    for (int q = 0; q < 4; ++q) {
        float vx = acc2[q].x * inv, vy = acc2[q].y * inv;
        o[2 * q]     = (vx + __shfl_xor(vx, 4)) * 0.5f;
        o[2 * q + 1] = (vy + __shfl_xor(vy, 4)) * 0.5f;
    }
    if (j < 4) {
        float4 b0 = ((const float4*)bias)[j * 2];
        float4 b1 = ((const float4*)bias)[j * 2 + 1];
        float4 r0, r1;
        r0.x = o[0] + b0.x; r0.y = o[1] + b0.y; r0.z = o[2] + b0.z; r0.w = o[3] + b0.w;
        r1.x = o[4] + b1.x; r1.y = o[5] + b1.y; r1.z = o[6] + b1.z; r1.w = o[7] + b1.w;
        r0.x = r0.x / (1.f + __expf(-r0.x));
        r0.y = r0.y / (1.f + __expf(-r0.y));
        r0.z = r0.z / (1.f + __expf(-r0.z));
        r0.w = r0.w / (1.f + __expf(-r0.w));
        r1.x = r1.x / (1.f + __expf(-r1.x));
        r1.y = r1.y / (1.f + __expf(-r1.y));
        r1.z = r1.z / (1.f + __expf(-r1.z));
        r1.w = r1.w / (1.f + __expf(-r1.w));
        ((float4*)out)[(size_t)n * 8 + j * 2] = r0;
        ((float4*)out)[(size_t)n * 8 + j * 2 + 1] = r1;
    }
}

extern "C" void kernel_launch(void* const* d_in, const int* in_sizes, int n_in,
                              void* d_out, int out_size, void* d_ws, size_t ws_size,
                              hipStream_t stream) {
    const float* x    = (const float*)d_in[0];
    const float* Wl   = (const float*)d_in[1];
    const float* bl   = (const float*)d_in[2];
    const float* Wr   = (const float*)d_in[3];
    const float* br   = (const float*)d_in[4];
    const float* att  = (const float*)d_in[5];
    const float* bias = (const float*)d_in[6];
    const int*   ei   = (const int*)d_in[7];
    float* out = (float*)d_out;

    const int N = in_sizes[0] / 128;
    const int E = in_sizes[7] / 2;
    const int T = E + N;                          // edges incl. self loops
    const int NB = (N + (1 << BSH) - 1) >> BSH;   // 196 buckets

    char* p = (char*)d_ws;
    auto take = [&](size_t bytes) {
        char* r = p;
        p += (bytes + 255) & ~(size_t)255;
        return r;
    };
    unsigned short* xlh = (unsigned short*)take((size_t)N * 64 * 2);
    float*    xr     = (float*)take((size_t)N * 64 * 4);
    unsigned* pairs  = (unsigned*)take((size_t)NB * CAP * 4);
    int*      src_s  = (int*)take((size_t)NB * CAP * 4);
    int2*     rowrng = (int2*)take((size_t)N * 8);
    int*      bcur   = (int*)take((size_t)NB * 4);
    unsigned short* Wt = (unsigned short*)take((size_t)128 * 128 * 2);

    const int GB = (N + 127) / 128;
    const int SB = (T + ACH - 1) / ACH;
    hipMemsetAsync(bcur, 0, (size_t)NB * 4, stream);
    k_prep <<<8,             256, 0, stream>>>(Wl, Wr, Wt);
    k_gs   <<<GB + SB,       256, 0, stream>>>(x, Wt, bl, br, xlh, xr, N,
                                               ei, bcur, pairs, E, T, NB, GB);
    k_scatB<<<NB,            512, 0, stream>>>(pairs, bcur, src_s, rowrng, N);
    k_fused<<<(N + 31) / 32, 256, 0, stream>>>(rowrng, src_s, xlh, xr, att, bias, out, N);
}

// Round 13
// 118.619 us; speedup vs baseline: 1.0281x; 1.0281x over previous
//
#include <hip/hip_runtime.h>
#include <math.h>

#define BSH 9                       // 512 nodes per bucket
#define BMASK ((1 << BSH) - 1)
#define CAP 12288                   // per-bucket pair capacity (mean 8676, sigma 93)
#define ACH 2048                    // edges per scatA block

typedef unsigned int uint;
typedef __attribute__((ext_vector_type(8))) short bf16x8;
typedef __attribute__((ext_vector_type(4))) float f32x4;
typedef __attribute__((ext_vector_type(2))) float f32x2;

static __device__ __forceinline__ unsigned short f2bf(float f) {
    uint u = __float_as_uint(f);
    return (unsigned short)((u + 0x7fffu + ((u >> 16) & 1u)) >> 16);
}

// pack 8 consecutive fp32 (two f32x4) -> bf16x8 via HW cvt (RNE), src0 -> low half
static __device__ __forceinline__ bf16x8 pack8(f32x4 a, f32x4 b) {
    uint p0, p1, p2, p3;
    asm("v_cvt_pk_bf16_f32 %0, %1, %2" : "=v"(p0) : "v"(a.x), "v"(a.y));
    asm("v_cvt_pk_bf16_f32 %0, %1, %2" : "=v"(p1) : "v"(a.z), "v"(a.w));
    asm("v_cvt_pk_bf16_f32 %0, %1, %2" : "=v"(p2) : "v"(b.x), "v"(b.y));
    asm("v_cvt_pk_bf16_f32 %0, %1, %2" : "=v"(p3) : "v"(b.z), "v"(b.w));
    uint4 u = make_uint4(p0, p1, p2, p3);
    return *(bf16x8*)&u;
}

static __device__ __forceinline__ f32x2 dec2(uint u) {
    f32x2 r;
    r.x = __uint_as_float(u << 16);
    r.y = __uint_as_float(u & 0xffff0000u);
    return r;
}

static __device__ __forceinline__ f32x2 abs2(f32x2 h) {
    f32x2 r;
    r.x = __uint_as_float(__float_as_uint(h.x) & 0x7fffffffu);
    r.y = __uint_as_float(__float_as_uint(h.y) & 0x7fffffffu);
    return r;
}

// sum over 4-lane quads via DPP (no LDS port): xor1 then xor2
static __device__ __forceinline__ float qsum(float p) {
    p += __uint_as_float(__builtin_amdgcn_mov_dpp(__float_as_uint(p), 0xB1, 0xF, 0xF, true));
    p += __uint_as_float(__builtin_amdgcn_mov_dpp(__float_as_uint(p), 0x4E, 0xF, 0xF, true));
    return p;
}

// ---------------- prep: fragment-major bf16 weight table ----------------
// Slot si = ks*512 + j*64 + hi*16 + lo (16B = 8 bf16) holds W^T[n=j*16+lo][k=ks*32+hi*8 .. +8],
// where cols n<64 come from Wl, n>=64 from Wr. A wave reading fragment (ks,j) then touches
// 64 consecutive slots = 1KB contiguous -> perfectly coalesced, L1-resident.
__global__ __launch_bounds__(256) void k_prep(const float* __restrict__ Wl,
                                              const float* __restrict__ Wr,
                                              unsigned short* __restrict__ Wt) {
    int si = blockIdx.x * 256 + threadIdx.x;   // 0..2047
    int lo = si & 15;
    int hi = (si >> 4) & 3;
    int j  = (si >> 6) & 7;
    int ks = si >> 9;
    int n  = j * 16 + lo;
    int kb = ks * 32 + hi * 8;
    const float* Wp = (n < 64) ? (Wl + n) : (Wr + (n - 64));
    unsigned short v[8];
#pragma unroll
    for (int m = 0; m < 8; ++m)
        v[m] = f2bf(Wp[(size_t)(kb + m) * 64]);
    uint4 pk;
    pk.x = (uint)v[0] | ((uint)v[1] << 16);
    pk.y = (uint)v[2] | ((uint)v[3] << 16);
    pk.z = (uint)v[4] | ((uint)v[5] << 16);
    pk.w = (uint)v[6] | ((uint)v[7] << 16);
    *(uint4*)(Wt + (size_t)si * 8) = pk;
}

// ---------------- MFMA dual GEMM body: [xlh|xrh] = bf16(x @ [Wl|Wr] + [bl|br]) ----------
// No LDS, no syncthreads. B fragments = coalesced 16B/lane reads from fragment-major Wt;
// A fragments = per-lane nontemporal x reads (stream once, keep Wt in L1) + cvt_pk.
static __device__ __forceinline__ void gemm_body(
        const float* __restrict__ x, const unsigned short* __restrict__ Wt,
        const float* __restrict__ bl, const float* __restrict__ br,
        unsigned short* __restrict__ xlh, unsigned short* __restrict__ xrh, int N, int bid)
{
    const int t = threadIdx.x;
    const int base = bid * 128;
    const int w = t >> 6;               // wave 0..3
    const int lo = t & 15;              // lane low bits: A-row / B-col / D-col
    const int hi = (t & 63) >> 4;       // lane high bits: k-group / D-row-group
    int row0 = base + w * 32 + lo;
    int row1 = row0 + 16;
    const f32x4* x40 = (const f32x4*)x + (size_t)(row0 < N ? row0 : N - 1) * 32;
    const f32x4* x41 = (const f32x4*)x + (size_t)(row1 < N ? row1 : N - 1) * 32;
    const bf16x8* Wf = (const bf16x8*)Wt;   // slot-indexed

    f32x4 acc[2][8];
#pragma unroll
    for (int f = 0; f < 2; ++f)
#pragma unroll
        for (int j = 0; j < 8; ++j)
            acc[f][j] = (f32x4){0.f, 0.f, 0.f, 0.f};

#pragma unroll
    for (int ks = 0; ks < 4; ++ks) {
        int f4 = ks * 8 + hi * 2;       // f32x4 col of this lane's 8 fp32 k-values
        int sbase = ks * 512 + hi * 16 + lo;
        bf16x8 av[2], bv[8];
        av[0] = pack8(__builtin_nontemporal_load(x40 + f4),
                      __builtin_nontemporal_load(x40 + f4 + 1));
        av[1] = pack8(__builtin_nontemporal_load(x41 + f4),
                      __builtin_nontemporal_load(x41 + f4 + 1));
#pragma unroll
        for (int j = 0; j < 8; ++j)
            bv[j] = Wf[sbase + j * 64];
#pragma unroll
        for (int f = 0; f < 2; ++f)
#pragma unroll
            for (int j = 0; j < 8; ++j)
                acc[f][j] = __builtin_amdgcn_mfma_f32_16x16x32_bf16(av[f], bv[j], acc[f][j], 0, 0, 0);
    }

    // ---- epilogue: D[m][n], m = rbase + reg, n = j*16+lo ----
#pragma unroll
    for (int f = 0; f < 2; ++f) {
        int rbase = base + w * 32 + f * 16 + hi * 4;
#pragma unroll
        for (int j = 0; j < 8; ++j) {
            int nn = j * 16 + lo;
            float bvv = (j < 4) ? bl[nn] : br[nn - 64];
            unsigned short* dst = (j < 4) ? (xlh + nn) : (xrh + (nn - 64));
#pragma unroll
            for (int q = 0; q < 4; ++q)
                if (rbase + q < N) dst[(size_t)(rbase + q) * 64] = f2bf(acc[f][j][q] + bvv);
        }
    }
}

// ---------------- scatA body: blocked coarse scatter into bucket-grouped packed pairs ----
// bcur starts at 0 (memset); bucket b's region is [b*CAP, b*CAP + count).
static __device__ __forceinline__ void scatA_body(
        const int* __restrict__ ei, int* __restrict__ bcur,
        unsigned* __restrict__ pairs, int E, int T, int NB, int bid)
{
    __shared__ int h[256];
    __shared__ int basem[256];
    int b0 = bid * ACH;
    int cnt = min(ACH, T - b0);
    h[threadIdx.x] = 0;
    __syncthreads();
    for (int i = threadIdx.x; i < cnt; i += 256) {
        int t = b0 + i;
        int d = (t < E) ? ei[E + t] : (t - E);
        atomicAdd(&h[d >> BSH], 1);
    }
    __syncthreads();
    if (threadIdx.x < NB) {
        int c = h[threadIdx.x];
        basem[threadIdx.x] = c ? (threadIdx.x * CAP + atomicAdd(&bcur[threadIdx.x], c)) : 0;
    }
    __syncthreads();
    h[threadIdx.x] = 0;
    __syncthreads();
    for (int i = threadIdx.x; i < cnt; i += 256) {
        int t = b0 + i;
        int s, d;
        if (t < E) { s = ei[t]; d = ei[E + t]; } else { s = t - E; d = s; }
        int b = d >> BSH;
        int idx = atomicAdd(&h[b], 1);
        pairs[basem[b] + idx] = ((unsigned)s << BSH) | (unsigned)(d & BMASK);
    }
}

// ---------------- fat kernel: blocks [0,GB) = gemm, [GB, GB+SB) = scatA ----------------
__global__ __launch_bounds__(256) void k_gs(const float* __restrict__ x,
        const unsigned short* __restrict__ Wt,
        const float* __restrict__ bl, const float* __restrict__ br,
        unsigned short* __restrict__ xlh, unsigned short* __restrict__ xrh, int N,
        const int* __restrict__ ei, int* __restrict__ bcur,
        unsigned* __restrict__ pairs, int E, int T, int NB, int GB)
{
    if ((int)blockIdx.x < GB)
        gemm_body(x, Wt, bl, br, xlh, xrh, N, blockIdx.x);
    else
        scatA_body(ei, bcur, pairs, E, T, NB, blockIdx.x - GB);
}

// ---------------- pass B: per-bucket degree count + scan + fine scatter + rowrng ----------------
__global__ __launch_bounds__(512) void k_scatB(const unsigned* __restrict__ pairs,
                                               const int* __restrict__ bcur,
                                               int* __restrict__ src_s, int2* __restrict__ rowrng, int N) {
    __shared__ int cnt[512];
    __shared__ int sm[512];
    __shared__ int lofs[512];
    int b = blockIdx.x;
    int beg = b * CAP, end = beg + bcur[b];
    int nbase = b << BSH;
    cnt[threadIdx.x] = 0;
    __syncthreads();
    for (int i = beg + threadIdx.x; i < end; i += 512)
        atomicAdd(&cnt[pairs[i] & BMASK], 1);
    __syncthreads();
    int v = cnt[threadIdx.x];
    sm[threadIdx.x] = v;
    __syncthreads();
    int acc = v;
    for (int off = 1; off < 512; off <<= 1) {
        int t = (threadIdx.x >= off) ? sm[threadIdx.x - off] : 0;
        __syncthreads();
        acc += t;
        sm[threadIdx.x] = acc;
        __syncthreads();
    }
    int excl = acc - v;
    lofs[threadIdx.x] = excl;
    int n = nbase + threadIdx.x;
    if (n < N) rowrng[n] = make_int2(beg + excl, beg + excl + v);
    cnt[threadIdx.x] = 0;
    __syncthreads();
    for (int i = beg + threadIdx.x; i < end; i += 512) {
        unsigned p = pairs[i];
        int dl = p & BMASK;
        int idx = atomicAdd(&cnt[dl], 1);
        src_s[beg + lofs[dl] + idx] = p >> BSH;
    }
}

// ---------------- fused attn + softmax + aggregation + silu ----------------
// 8 lanes per node, 8 channels per lane (bf16 gathers, 16 B/lane/edge).
// Lanes 0-3 = head0, lanes 4-7 = head1. 8 edges in flight.
// Packed f32x2 math; lrelu folded: att.lrelu(h) = (0.6 att).h + (0.4 att).|h|
__global__ __launch_bounds__(256) void k_fused(const int2* __restrict__ rowrng,
        const int* __restrict__ src_s, const unsigned short* __restrict__ xlh,
        const unsigned short* __restrict__ xrh, const float* __restrict__ att,
        const float* __restrict__ bias, float* __restrict__ out, int N)
{
    int n = blockIdx.x * 32 + (threadIdx.x >> 3);
    int j = threadIdx.x & 7;
    if (n >= N) return;
    const uint4* xl4 = (const uint4*)xlh + j;
    f32x2 xr2[4], a06[4], a04[4];
    {
        uint4 u = ((const uint4*)xrh)[(size_t)n * 8 + j];
        xr2[0] = dec2(u.x); xr2[1] = dec2(u.y);
        xr2[2] = dec2(u.z); xr2[3] = dec2(u.w);
        float4 c = ((const float4*)att)[j * 2];
        float4 d = ((const float4*)att)[j * 2 + 1];
        a06[0] = (f32x2){0.6f * c.x, 0.6f * c.y}; a06[1] = (f32x2){0.6f * c.z, 0.6f * c.w};
        a06[2] = (f32x2){0.6f * d.x, 0.6f * d.y}; a06[3] = (f32x2){0.6f * d.z, 0.6f * d.w};
        a04[0] = (f32x2){0.4f * c.x, 0.4f * c.y}; a04[1] = (f32x2){0.4f * c.z, 0.4f * c.w};
        a04[2] = (f32x2){0.4f * d.x, 0.4f * d.y}; a04[3] = (f32x2){0.4f * d.z, 0.4f * d.w};
    }
    int2 rr = rowrng[n];
    float ssum = 0.f;
    f32x2 acc2[4] = {(f32x2){0.f,0.f}, (f32x2){0.f,0.f}, (f32x2){0.f,0.f}, (f32x2){0.f,0.f}};

#define EDGE_BODY(u)                                                      \
    {                                                                     \
        f32x2 v0 = dec2((u).x), v1 = dec2((u).y), v2 = dec2((u).z), v3 = dec2((u).w); \
        f32x2 h0 = v0 + xr2[0], h1 = v1 + xr2[1], h2 = v2 + xr2[2], h3 = v3 + xr2[3]; \
        f32x2 pa = h0 * a06[0]; pa += h1 * a06[1]; pa += h2 * a06[2]; pa += h3 * a06[3]; \
        pa += abs2(h0) * a04[0]; pa += abs2(h1) * a04[1];                 \
        pa += abs2(h2) * a04[2]; pa += abs2(h3) * a04[3];                 \
        float p = pa.x + pa.y;                                            \
        p = qsum(p);                                                      \
        float wq = __expf(p);                                             \
        ssum += wq;                                                       \
        f32x2 ws = (f32x2){wq, wq};                                       \
        acc2[0] += ws * v0; acc2[1] += ws * v1;                           \
        acc2[2] += ws * v2; acc2[3] += ws * v3;                           \
    }

    int i = rr.x;
    for (; i + 8 <= rr.y; i += 8) {
        uint4 u[8];
#pragma unroll
        for (int q = 0; q < 8; ++q)
            u[q] = xl4[((uint)src_s[i + q] << 3)];
#pragma unroll
        for (int q = 0; q < 8; ++q)
            EDGE_BODY(u[q]);
    }
    if (i + 4 <= rr.y) {
        uint4 u[4];
#pragma unroll
        for (int q = 0; q < 4; ++q)
            u[q] = xl4[((uint)src_s[i + q] << 3)];
#pragma unroll
        for (int q = 0; q < 4; ++q)
            EDGE_BODY(u[q]);
        i += 4;
    }
    for (; i < rr.y; ++i) {
        uint4 u0 = xl4[((uint)src_s[i] << 3)];
        EDGE_BODY(u0);
    }
#undef EDGE_BODY

    float inv = 1.f / ssum;
    float o[8];
#pragma unroll
    for (int q = 0; q < 4; ++q) {
        float vx = acc2[q].x * inv, vy = acc2[q].y * inv;
        o[2 * q]     = (vx + __shfl_xor(vx, 4)) * 0.5f;
        o[2 * q + 1] = (vy + __shfl_xor(vy, 4)) * 0.5f;
    }
    if (j < 4) {
        float4 b0 = ((const float4*)bias)[j * 2];
        float4 b1 = ((const float4*)bias)[j * 2 + 1];
        float4 r0, r1;
        r0.x = o[0] + b0.x; r0.y = o[1] + b0.y; r0.z = o[2] + b0.z; r0.w = o[3] + b0.w;
        r1.x = o[4] + b1.x; r1.y = o[5] + b1.y; r1.z = o[6] + b1.z; r1.w = o[7] + b1.w;
        r0.x = r0.x / (1.f + __expf(-r0.x));
        r0.y = r0.y / (1.f + __expf(-r0.y));
        r0.z = r0.z / (1.f + __expf(-r0.z));
        r0.w = r0.w / (1.f + __expf(-r0.w));
        r1.x = r1.x / (1.f + __expf(-r1.x));
        r1.y = r1.y / (1.f + __expf(-r1.y));
        r1.z = r1.z / (1.f + __expf(-r1.z));
        r1.w = r1.w / (1.f + __expf(-r1.w));
        ((float4*)out)[(size_t)n * 8 + j * 2] = r0;
        ((float4*)out)[(size_t)n * 8 + j * 2 + 1] = r1;
    }
}

extern "C" void kernel_launch(void* const* d_in, const int* in_sizes, int n_in,
                              void* d_out, int out_size, void* d_ws, size_t ws_size,
                              hipStream_t stream) {
    const float* x    = (const float*)d_in[0];
    const float* Wl   = (const float*)d_in[1];
    const float* bl   = (const float*)d_in[2];
    const float* Wr   = (const float*)d_in[3];
    const float* br   = (const float*)d_in[4];
    const float* att  = (const float*)d_in[5];
    const float* bias = (const float*)d_in[6];
    const int*   ei   = (const int*)d_in[7];
    float* out = (float*)d_out;

    const int N = in_sizes[0] / 128;
    const int E = in_sizes[7] / 2;
    const int T = E + N;                          // edges incl. self loops
    const int NB = (N + (1 << BSH) - 1) >> BSH;   // 196 buckets

    char* p = (char*)d_ws;
    auto take = [&](size_t bytes) {
        char* r = p;
        p += (bytes + 255) & ~(size_t)255;
        return r;
    };
    unsigned short* xlh = (unsigned short*)take((size_t)N * 64 * 2);
    unsigned short* xrh = (unsigned short*)take((size_t)N * 64 * 2);
    unsigned* pairs  = (unsigned*)take((size_t)NB * CAP * 4);
    int*      src_s  = (int*)take((size_t)NB * CAP * 4);
    int2*     rowrng = (int2*)take((size_t)N * 8);
    int*      bcur   = (int*)take((size_t)NB * 4);
    unsigned short* Wt = (unsigned short*)take((size_t)128 * 128 * 2);

    const int GB = (N + 127) / 128;
    const int SB = (T + ACH - 1) / ACH;
    hipMemsetAsync(bcur, 0, (size_t)NB * 4, stream);
    k_prep <<<8,             256, 0, stream>>>(Wl, Wr, Wt);
    k_gs   <<<GB + SB,       256, 0, stream>>>(x, Wt, bl, br, xlh, xrh, N,
                                               ei, bcur, pairs, E, T, NB, GB);
    k_scatB<<<NB,            512, 0, stream>>>(pairs, bcur, src_s, rowrng, N);
    k_fused<<<(N + 31) / 32, 256, 0, stream>>>(rowrng, src_s, xlh, xrh, att, bias, out, N);
}

// Round 14
// 110.442 us; speedup vs baseline: 1.1042x; 1.0740x over previous
//
#include <hip/hip_runtime.h>
#include <math.h>

#define BSH 9                       // 512 nodes per bucket
#define BMASK ((1 << BSH) - 1)
#define CAP 12288                   // per-bucket pair capacity (mean 8676, sigma 93)
#define ACH 8192                    // edges per scatA block

typedef unsigned int uint;
typedef __attribute__((ext_vector_type(8))) short bf16x8;
typedef __attribute__((ext_vector_type(4))) float f32x4;
typedef __attribute__((ext_vector_type(2))) float f32x2;

static __device__ __forceinline__ unsigned short f2bf(float f) {
    uint u = __float_as_uint(f);
    return (unsigned short)((u + 0x7fffu + ((u >> 16) & 1u)) >> 16);
}

// pack 8 consecutive fp32 (two f32x4) -> bf16x8 via HW cvt (RNE), src0 -> low half
static __device__ __forceinline__ bf16x8 pack8(f32x4 a, f32x4 b) {
    uint p0, p1, p2, p3;
    asm("v_cvt_pk_bf16_f32 %0, %1, %2" : "=v"(p0) : "v"(a.x), "v"(a.y));
    asm("v_cvt_pk_bf16_f32 %0, %1, %2" : "=v"(p1) : "v"(a.z), "v"(a.w));
    asm("v_cvt_pk_bf16_f32 %0, %1, %2" : "=v"(p2) : "v"(b.x), "v"(b.y));
    asm("v_cvt_pk_bf16_f32 %0, %1, %2" : "=v"(p3) : "v"(b.z), "v"(b.w));
    uint4 u = make_uint4(p0, p1, p2, p3);
    return *(bf16x8*)&u;
}

static __device__ __forceinline__ uint pk2(float a, float b) {
    uint d;
    asm("v_cvt_pk_bf16_f32 %0, %1, %2" : "=v"(d) : "v"(a), "v"(b));
    return d;
}

static __device__ __forceinline__ f32x2 dec2(uint u) {
    f32x2 r;
    r.x = __uint_as_float(u << 16);
    r.y = __uint_as_float(u & 0xffff0000u);
    return r;
}

static __device__ __forceinline__ f32x2 abs2(f32x2 h) {
    f32x2 r;
    r.x = __uint_as_float(__float_as_uint(h.x) & 0x7fffffffu);
    r.y = __uint_as_float(__float_as_uint(h.y) & 0x7fffffffu);
    return r;
}

// sum over 4-lane quads via DPP (no LDS port): xor1 then xor2
static __device__ __forceinline__ float qsum(float p) {
    p += __uint_as_float(__builtin_amdgcn_mov_dpp(__float_as_uint(p), 0xB1, 0xF, 0xF, true));
    p += __uint_as_float(__builtin_amdgcn_mov_dpp(__float_as_uint(p), 0x4E, 0xF, 0xF, true));
    return p;
}

// ---------------- prep: fragment-major bf16 weight table ----------------
// Slot si = ks*512 + j*64 + hi*16 + lo holds W^T[n=j*16+lo][k=ks*32+hi*8 .. +8].
__global__ __launch_bounds__(256) void k_prep(const float* __restrict__ Wl,
                                              const float* __restrict__ Wr,
                                              unsigned short* __restrict__ Wt) {
    int si = blockIdx.x * 256 + threadIdx.x;   // 0..2047
    int lo = si & 15;
    int hi = (si >> 4) & 3;
    int j  = (si >> 6) & 7;
    int ks = si >> 9;
    int n  = j * 16 + lo;
    int kb = ks * 32 + hi * 8;
    const float* Wp = (n < 64) ? (Wl + n) : (Wr + (n - 64));
    unsigned short v[8];
#pragma unroll
    for (int m = 0; m < 8; ++m)
        v[m] = f2bf(Wp[(size_t)(kb + m) * 64]);
    uint4 pk;
    pk.x = (uint)v[0] | ((uint)v[1] << 16);
    pk.y = (uint)v[2] | ((uint)v[3] << 16);
    pk.z = (uint)v[4] | ((uint)v[5] << 16);
    pk.w = (uint)v[6] | ((uint)v[7] << 16);
    *(uint4*)(Wt + (size_t)si * 8) = pk;
}

// ---------------- MFMA dual GEMM body -------------------------------------------------
// Output row layout (both xlh and xrh), co-designed with k_fused:
//   position 2*lo + t      (t=0,1)  <-> col t*16 + lo      (head 0)
//   position 32 + 2*lo + t (t=0,1)  <-> col 32 + t*16 + lo (head 1)
// Epilogue: cvt_pk dword stores; a wave-store covers 4 rows x 64B contiguous.
static __device__ __forceinline__ void gemm_body(
        const float* __restrict__ x, const unsigned short* __restrict__ Wt,
        const float* __restrict__ bl, const float* __restrict__ br,
        unsigned short* __restrict__ xlh, unsigned short* __restrict__ xrh, int N, int bid)
{
    const int t = threadIdx.x;
    const int base = bid * 128;
    const int w = t >> 6;               // wave 0..3
    const int lo = t & 15;              // lane low bits
    const int hi = (t & 63) >> 4;       // lane high bits
    int row0 = base + w * 32 + lo;
    int row1 = row0 + 16;
    const f32x4* x40 = (const f32x4*)x + (size_t)(row0 < N ? row0 : N - 1) * 32;
    const f32x4* x41 = (const f32x4*)x + (size_t)(row1 < N ? row1 : N - 1) * 32;
    const bf16x8* Wf = (const bf16x8*)Wt;

    f32x4 acc[2][8];
#pragma unroll
    for (int f = 0; f < 2; ++f)
#pragma unroll
        for (int j = 0; j < 8; ++j)
            acc[f][j] = (f32x4){0.f, 0.f, 0.f, 0.f};

#pragma unroll
    for (int ks = 0; ks < 4; ++ks) {
        int f4 = ks * 8 + hi * 2;
        int sbase = ks * 512 + hi * 16 + lo;
        bf16x8 av[2], bv[8];
        av[0] = pack8(x40[f4], x40[f4 + 1]);
        av[1] = pack8(x41[f4], x41[f4 + 1]);
#pragma unroll
        for (int j = 0; j < 8; ++j)
            bv[j] = Wf[sbase + j * 64];
#pragma unroll
        for (int f = 0; f < 2; ++f)
#pragma unroll
            for (int j = 0; j < 8; ++j)
                acc[f][j] = __builtin_amdgcn_mfma_f32_16x16x32_bf16(av[f], bv[j], acc[f][j], 0, 0, 0);
    }

    // ---- epilogue ----
    float blv[4], brv[4];
#pragma unroll
    for (int t2 = 0; t2 < 4; ++t2) {
        blv[t2] = bl[t2 * 16 + lo];
        brv[t2] = br[t2 * 16 + lo];
    }
#pragma unroll
    for (int f = 0; f < 2; ++f) {
#pragma unroll
        for (int q = 0; q < 4; ++q) {
            int row = base + w * 32 + f * 16 + hi * 4 + q;
            if (row < N) {
                size_t rb = (size_t)row * 64;
                *(uint*)(xlh + rb + 2 * lo)      = pk2(acc[f][0][q] + blv[0], acc[f][1][q] + blv[1]);
                *(uint*)(xlh + rb + 32 + 2 * lo) = pk2(acc[f][2][q] + blv[2], acc[f][3][q] + blv[3]);
                *(uint*)(xrh + rb + 2 * lo)      = pk2(acc[f][4][q] + brv[0], acc[f][5][q] + brv[1]);
                *(uint*)(xrh + rb + 32 + 2 * lo) = pk2(acc[f][6][q] + brv[2], acc[f][7][q] + brv[3]);
            }
        }
    }
}

// ---------------- scatA body: blocked coarse scatter into bucket-grouped packed pairs ----
static __device__ __forceinline__ void scatA_body(
        const int* __restrict__ ei, int* __restrict__ bcur,
        unsigned* __restrict__ pairs, int E, int T, int NB, int bid)
{
    __shared__ int h[256];
    __shared__ int basem[256];
    int b0 = bid * ACH;
    int cnt = min(ACH, T - b0);
    h[threadIdx.x] = 0;
    __syncthreads();
    for (int i = threadIdx.x; i < cnt; i += 256) {
        int t = b0 + i;
        int d = (t < E) ? ei[E + t] : (t - E);
        atomicAdd(&h[d >> BSH], 1);
    }
    __syncthreads();
    if (threadIdx.x < NB) {
        int c = h[threadIdx.x];
        basem[threadIdx.x] = c ? (threadIdx.x * CAP + atomicAdd(&bcur[threadIdx.x], c)) : 0;
    }
    __syncthreads();
    h[threadIdx.x] = 0;
    __syncthreads();
    for (int i = threadIdx.x; i < cnt; i += 256) {
        int t = b0 + i;
        int s, d;
        if (t < E) { s = ei[t]; d = ei[E + t]; } else { s = t - E; d = s; }
        int b = d >> BSH;
        int idx = atomicAdd(&h[b], 1);
        pairs[basem[b] + idx] = ((unsigned)s << BSH) | (unsigned)(d & BMASK);
    }
}

// ---------------- fat kernel: Bresenham-interleaved gemm / scatA roles ----------------
__global__ __launch_bounds__(256) void k_gs(const float* __restrict__ x,
        const unsigned short* __restrict__ Wt,
        const float* __restrict__ bl, const float* __restrict__ br,
        unsigned short* __restrict__ xlh, unsigned short* __restrict__ xrh, int N,
        const int* __restrict__ ei, int* __restrict__ bcur,
        unsigned* __restrict__ pairs, int E, int T, int NB, int SB, int R)
{
    int bid = blockIdx.x;
    int sbef = (int)(((long long)bid * SB) / R);
    int snow = (int)(((long long)(bid + 1) * SB) / R);
    if (snow > sbef)
        scatA_body(ei, bcur, pairs, E, T, NB, sbef);
    else
        gemm_body(x, Wt, bl, br, xlh, xrh, N, bid - sbef);
}

// ---------------- pass B: per-bucket degree count + scan + fine scatter + rowrng ----------------
__global__ __launch_bounds__(512) void k_scatB(const unsigned* __restrict__ pairs,
                                               const int* __restrict__ bcur,
                                               int* __restrict__ src_s, int2* __restrict__ rowrng, int N) {
    __shared__ int cnt[512];
    __shared__ int sm[512];
    __shared__ int lofs[512];
    int b = blockIdx.x;
    int beg = b * CAP, end = beg + bcur[b];
    int nbase = b << BSH;
    cnt[threadIdx.x] = 0;
    __syncthreads();
    for (int i = beg + threadIdx.x; i < end; i += 512)
        atomicAdd(&cnt[pairs[i] & BMASK], 1);
    __syncthreads();
    int v = cnt[threadIdx.x];
    sm[threadIdx.x] = v;
    __syncthreads();
    int acc = v;
    for (int off = 1; off < 512; off <<= 1) {
        int t = (threadIdx.x >= off) ? sm[threadIdx.x - off] : 0;
        __syncthreads();
        acc += t;
        sm[threadIdx.x] = acc;
        __syncthreads();
    }
    int excl = acc - v;
    lofs[threadIdx.x] = excl;
    int n = nbase + threadIdx.x;
    if (n < N) rowrng[n] = make_int2(beg + excl, beg + excl + v);
    cnt[threadIdx.x] = 0;
    __syncthreads();
    for (int i = beg + threadIdx.x; i < end; i += 512) {
        unsigned p = pairs[i];
        int dl = p & BMASK;
        int idx = atomicAdd(&cnt[dl], 1);
        src_s[beg + lofs[dl] + idx] = p >> BSH;
    }
}

// ---------------- fused attn + softmax + aggregation + silu ----------------
// 8 lanes per node; lanes 0-3 head0, 4-7 head1 (head-blocked transposed row layout).
// Lane jf reads uint4 position block 8*jf: position p = 8*jf + m <-> col
// hsel*32 + (m&1)*16 + 4*(jf&3) + (m>>1).
__global__ __launch_bounds__(256) void k_fused(const int2* __restrict__ rowrng,
        const int* __restrict__ src_s, const unsigned short* __restrict__ xlh,
        const unsigned short* __restrict__ xrh, const float* __restrict__ att,
        const float* __restrict__ bias, float* __restrict__ out, int N)
{
    int n = blockIdx.x * 32 + (threadIdx.x >> 3);
    int jf = threadIdx.x & 7;
    if (n >= N) return;
    int hsel = jf >> 2, l4 = jf & 3;
    const uint4* xl4 = (const uint4*)xlh + jf;
    f32x2 xr2[4], a06[4], a04[4];
    {
        uint4 u = ((const uint4*)xrh)[(size_t)n * 8 + jf];
        xr2[0] = dec2(u.x); xr2[1] = dec2(u.y);
        xr2[2] = dec2(u.z); xr2[3] = dec2(u.w);
        int cb = hsel * 32 + 4 * l4;
#pragma unroll
        for (int k = 0; k < 4; ++k) {
            float c0 = att[cb + k], c1 = att[cb + 16 + k];
            a06[k] = (f32x2){0.6f * c0, 0.6f * c1};
            a04[k] = (f32x2){0.4f * c0, 0.4f * c1};
        }
    }
    int2 rr = rowrng[n];
    float ssum = 0.f;
    f32x2 acc2[4] = {(f32x2){0.f,0.f}, (f32x2){0.f,0.f}, (f32x2){0.f,0.f}, (f32x2){0.f,0.f}};

#define EDGE_BODY(u)                                                      \
    {                                                                     \
        f32x2 v0 = dec2((u).x), v1 = dec2((u).y), v2 = dec2((u).z), v3 = dec2((u).w); \
        f32x2 h0 = v0 + xr2[0], h1 = v1 + xr2[1], h2 = v2 + xr2[2], h3 = v3 + xr2[3]; \
        f32x2 pa = h0 * a06[0]; pa += h1 * a06[1]; pa += h2 * a06[2]; pa += h3 * a06[3]; \
        pa += abs2(h0) * a04[0]; pa += abs2(h1) * a04[1];                 \
        pa += abs2(h2) * a04[2]; pa += abs2(h3) * a04[3];                 \
        float p = pa.x + pa.y;                                            \
        p = qsum(p);                                                      \
        float wq = __expf(p);                                             \
        ssum += wq;                                                       \
        f32x2 ws = (f32x2){wq, wq};                                       \
        acc2[0] += ws * v0; acc2[1] += ws * v1;                           \
        acc2[2] += ws * v2; acc2[3] += ws * v3;                           \
    }

    int i = rr.x;
    for (; i + 8 <= rr.y; i += 8) {
        uint4 u[8];
#pragma unroll
        for (int q = 0; q < 8; ++q)
            u[q] = xl4[((uint)src_s[i + q] << 3)];
#pragma unroll
        for (int q = 0; q < 8; ++q)
            EDGE_BODY(u[q]);
    }
    if (i + 4 <= rr.y) {
        uint4 u[4];
#pragma unroll
        for (int q = 0; q < 4; ++q)
            u[q] = xl4[((uint)src_s[i + q] << 3)];
#pragma unroll
        for (int q = 0; q < 4; ++q)
            EDGE_BODY(u[q]);
        i += 4;
    }
    for (; i < rr.y; ++i) {
        uint4 u0 = xl4[((uint)src_s[i] << 3)];
        EDGE_BODY(u0);
    }
#undef EDGE_BODY

    float inv = 1.f / ssum;
    float o[8];
#pragma unroll
    for (int q = 0; q < 4; ++q) {
        float vx = acc2[q].x * inv, vy = acc2[q].y * inv;
        o[2 * q]     = (vx + __shfl_xor(vx, 4)) * 0.5f;   // head-mean: partner holds col+32
        o[2 * q + 1] = (vy + __shfl_xor(vy, 4)) * 0.5f;
    }
    if (jf < 4) {
        // o[m]: out col (m&1)*16 + 4*l4 + (m>>1); regroup even/odd m into two float4s
        float4 b0 = ((const float4*)bias)[l4];
        float4 b1 = *(const float4*)(bias + 16 + 4 * l4);
        float4 r0, r1;
        r0.x = o[0] + b0.x; r0.y = o[2] + b0.y; r0.z = o[4] + b0.z; r0.w = o[6] + b0.w;
        r1.x = o[1] + b1.x; r1.y = o[3] + b1.y; r1.z = o[5] + b1.z; r1.w = o[7] + b1.w;
        r0.x = r0.x / (1.f + __expf(-r0.x));
        r0.y = r0.y / (1.f + __expf(-r0.y));
        r0.z = r0.z / (1.f + __expf(-r0.z));
        r0.w = r0.w / (1.f + __expf(-r0.w));
        r1.x = r1.x / (1.f + __expf(-r1.x));
        r1.y = r1.y / (1.f + __expf(-r1.y));
        r1.z = r1.z / (1.f + __expf(-r1.z));
        r1.w = r1.w / (1.f + __expf(-r1.w));
        ((float4*)out)[(size_t)n * 8 + l4]     = r0;
        ((float4*)out)[(size_t)n * 8 + 4 + l4] = r1;
    }
}

extern "C" void kernel_launch(void* const* d_in, const int* in_sizes, int n_in,
                              void* d_out, int out_size, void* d_ws, size_t ws_size,
                              hipStream_t stream) {
    const float* x    = (const float*)d_in[0];
    const float* Wl   = (const float*)d_in[1];
    const float* bl   = (const float*)d_in[2];
    const float* Wr   = (const float*)d_in[3];
    const float* br   = (const float*)d_in[4];
    const float* att  = (const float*)d_in[5];
    const float* bias = (const float*)d_in[6];
    const int*   ei   = (const int*)d_in[7];
    float* out = (float*)d_out;

    const int N = in_sizes[0] / 128;
    const int E = in_sizes[7] / 2;
    const int T = E + N;                          // edges incl. self loops
    const int NB = (N + (1 << BSH) - 1) >> BSH;   // 196 buckets

    char* p = (char*)d_ws;
    auto take = [&](size_t bytes) {
        char* r = p;
        p += (bytes + 255) & ~(size_t)255;
        return r;
    };
    unsigned short* xlh = (unsigned short*)take((size_t)N * 64 * 2);
    unsigned short* xrh = (unsigned short*)take((size_t)N * 64 * 2);
    unsigned* pairs  = (unsigned*)take((size_t)NB * CAP * 4);
    int*      src_s  = (int*)take((size_t)NB * CAP * 4);
    int2*     rowrng = (int2*)take((size_t)N * 8);
    int*      bcur   = (int*)take((size_t)NB * 4);
    unsigned short* Wt = (unsigned short*)take((size_t)128 * 128 * 2);

    const int GB = (N + 127) / 128;
    const int SB = (T + ACH - 1) / ACH;
    const int R  = GB + SB;
    hipMemsetAsync(bcur, 0, (size_t)NB * 4, stream);
    k_prep <<<8,             256, 0, stream>>>(Wl, Wr, Wt);
    k_gs   <<<R,             256, 0, stream>>>(x, Wt, bl, br, xlh, xrh, N,
                                               ei, bcur, pairs, E, T, NB, SB, R);
    k_scatB<<<NB,            512, 0, stream>>>(pairs, bcur, src_s, rowrng, N);
    k_fused<<<(N + 31) / 32, 256, 0, stream>>>(rowrng, src_s, xlh, xrh, att, bias, out, N);
}